// Round 1
// baseline (66.661 us; speedup 1.0000x reference)
//
#include <hip/hip_runtime.h>

// DCN cross layer: x_l = x_0 * (x_l . W[i]) + b_lin[i] + bias[i] + x_l, i=0..L-1
// B=8192, D=256, L=4, fp32.
// One 64-lane wave per row; each lane owns 4 contiguous floats (float4).
// Dot product via 6-step __shfl_xor wave reduction. x0/xl stay in registers.

__global__ __launch_bounds__(256) void cross_kernel(
    const float* __restrict__ x,
    const float* __restrict__ W,
    const float* __restrict__ b_lin,
    const float* __restrict__ bias,
    float* __restrict__ out,
    int B, int L)
{
    const int wave = threadIdx.x >> 6;     // 0..3
    const int lane = threadIdx.x & 63;     // 0..63
    const int row  = blockIdx.x * 4 + wave;
    if (row >= B) return;

    const float4* xrow = (const float4*)(x + (size_t)row * 256);
    float4 x0 = xrow[lane];
    float4 xl = x0;

    #pragma unroll
    for (int i = 0; i < 4; ++i) {
        if (i >= L) break;
        // per-lane partial dot of this lane's 4 elements
        float4 w = ((const float4*)(W + i * 256))[lane];
        float p = xl.x * w.x + xl.y * w.y + xl.z * w.z + xl.w * w.w;
        // reduce across 64 lanes
        #pragma unroll
        for (int off = 32; off > 0; off >>= 1)
            p += __shfl_xor(p, off, 64);
        const float s = p;                 // x_l . W[i], same in all lanes

        float4 bi = ((const float4*)(bias + i * 256))[lane];
        const float bl = b_lin[i];

        xl.x = fmaf(x0.x, s, bl + bi.x + xl.x);
        xl.y = fmaf(x0.y, s, bl + bi.y + xl.y);
        xl.z = fmaf(x0.z, s, bl + bi.z + xl.z);
        xl.w = fmaf(x0.w, s, bl + bi.w + xl.w);
    }

    ((float4*)(out + (size_t)row * 256))[lane] = xl;
}

extern "C" void kernel_launch(void* const* d_in, const int* in_sizes, int n_in,
                              void* d_out, int out_size, void* d_ws, size_t ws_size,
                              hipStream_t stream) {
    const float* x     = (const float*)d_in[0];
    const float* W     = (const float*)d_in[1];
    const float* b_lin = (const float*)d_in[2];
    const float* bias  = (const float*)d_in[3];
    float* out = (float*)d_out;

    const int L = in_sizes[2];          // 4
    const int D = in_sizes[1] / L;      // 256 (kernel assumes 256)
    const int B = in_sizes[0] / D;      // 8192

    const int rows_per_block = 4;       // 4 waves of 64 lanes
    const int grid = (B + rows_per_block - 1) / rows_per_block;
    cross_kernel<<<grid, 256, 0, stream>>>(x, W, b_lin, bias, out, B, L);
}